// Round 3
// baseline (12.405 us; speedup 1.0000x reference)
//
#include <hip/hip_runtime.h>
#include <math.h>

#define N_SUB 128

struct CM { float r00,i00,r01,i01,r10,i10,r11,i11; };

// C = A @ B (complex 2x2), fp32
__device__ inline CM cmm(const CM& A, const CM& B) {
    CM C;
    C.r00 = A.r00*B.r00 - A.i00*B.i00 + A.r01*B.r10 - A.i01*B.i10;
    C.i00 = A.r00*B.i00 + A.i00*B.r00 + A.r01*B.i10 + A.i01*B.r10;
    C.r01 = A.r00*B.r01 - A.i00*B.i01 + A.r01*B.r11 - A.i01*B.i11;
    C.i01 = A.r00*B.i01 + A.i00*B.r01 + A.r01*B.i11 + A.i01*B.r11;
    C.r10 = A.r10*B.r00 - A.i10*B.i00 + A.r11*B.r10 - A.i11*B.i10;
    C.i10 = A.r10*B.i00 + A.i10*B.r00 + A.r11*B.i10 + A.i11*B.r10;
    C.r11 = A.r10*B.r01 - A.i10*B.i01 + A.r11*B.r11 - A.i11*B.i11;
    C.i11 = A.r10*B.i01 + A.i10*B.r01 + A.r11*B.i11 + A.i11*B.r11;
    return C;
}

__device__ inline CM shfl_xor_cm(const CM& P, int mask) {
    CM Q;
    Q.r00 = __shfl_xor(P.r00, mask, 64); Q.i00 = __shfl_xor(P.i00, mask, 64);
    Q.r01 = __shfl_xor(P.r01, mask, 64); Q.i01 = __shfl_xor(P.i01, mask, 64);
    Q.r10 = __shfl_xor(P.r10, mask, 64); Q.i10 = __shfl_xor(P.i10, mask, 64);
    Q.r11 = __shfl_xor(P.r11, mask, 64); Q.i11 = __shfl_xor(P.i11, mask, 64);
    return Q;
}

__device__ inline CM buildT(int j, float d1v, float sqf, float dL,
                            float cb, float sb) {
    const float PI  = 3.14159265358979323846f;
    const float C1  = 1.2929f * 343.37f / PI;   // RHO*C/pi
    const float IC1 = PI / (1.2929f * 343.37f); // pi/(RHO*C)

    float t = ((float)j + 0.5f) * (1.0f / (float)N_SUB);
    float r = (32.0f + (d1v - 32.0f) * t) * (1.0f / 2000.0f);
    float rinv = __builtin_amdgcn_rcpf(r);      // ~1 ulp, plenty here
    float a = 3e-5f * sqf * rinv * dL;          // alpha*dL, |a| << 1e-3
    float a2 = a * a;
    // cosh/sinh of the tiny real part via short Taylor (exact at fp32)
    float cha = 1.0f + a2 * (0.5f + a2 * (1.0f/24.0f));
    float sha = a * (1.0f + a2 * (1.0f/6.0f + a2 * (1.0f/120.0f)));

    // cosh(a+ib) = cha*cb + i*sha*sb ; sinh(a+ib) = sha*cb + i*cha*sb
    float chr = cha * cb, chi = sha * sb;
    float shr = sha * cb, shi = cha * sb;

    float Z0  = C1 * rinv * rinv;
    float iZ0 = r * r * IC1;

    CM T;
    T.r00 = chr;       T.i00 = chi;
    T.r01 = Z0 * shr;  T.i01 = Z0 * shi;
    T.r10 = iZ0 * shr; T.i10 = iZ0 * shi;
    T.r11 = chr;       T.i11 = chi;
    return T;
}

// One wave (64 lanes) per frequency; lane l owns segments 2l, 2l+1;
// 6-level ordered butterfly product across the wave.
__global__ void didge_kernel(const float* __restrict__ length,
                             const float* __restrict__ d1p,
                             const int* __restrict__ fmin_p,
                             float* __restrict__ out, int out_n) {
    int gtid = blockIdx.x * blockDim.x + threadIdx.x;
    int wave = gtid >> 6;       // one frequency per wave
    int lane = gtid & 63;
    if (wave >= out_n) return;  // wave-uniform exit

    const float PI = 3.14159265358979323846f;
    const float C_SOUND = 343.37f;
    const float C1 = 1.2929f * C_SOUND / PI;

    const float f   = (float)fmin_p[0] + (float)wave;
    const float L_m = length[0] * (10.0f / 1000.0f);
    const float d1v = d1p[0];
    const float dL  = L_m * (1.0f / (float)N_SUB);
    const float k   = 2.0f * PI * f * (1.0f / C_SOUND);

    const float b = k * dL;     // segment-independent imaginary part
    float sb, cb;
    __sincosf(b, &sb, &cb);     // hardware v_sin/v_cos path
    const float sqf = __builtin_amdgcn_sqrtf(f);

    // Per-lane pair product: P = T_{2l} @ T_{2l+1}
    CM P = cmm(buildT(2*lane,     d1v, sqf, dL, cb, sb),
               buildT(2*lane + 1, d1v, sqf, dL, cb, sb));

    // Ordered tree: after level s, every lane in an aligned 2^(s+1) group
    // holds that group's full left-to-right product.
    #pragma unroll
    for (int s = 0; s < 6; ++s) {
        int m = 1 << s;
        CM Q = shfl_xor_cm(P, m);
        bool left = (lane & m) == 0;      // our group is the left operand?
        CM Lm, Rm;
        Lm.r00 = left ? P.r00 : Q.r00; Lm.i00 = left ? P.i00 : Q.i00;
        Lm.r01 = left ? P.r01 : Q.r01; Lm.i01 = left ? P.i01 : Q.i01;
        Lm.r10 = left ? P.r10 : Q.r10; Lm.i10 = left ? P.i10 : Q.i10;
        Lm.r11 = left ? P.r11 : Q.r11; Lm.i11 = left ? P.i11 : Q.i11;
        Rm.r00 = left ? Q.r00 : P.r00; Rm.i00 = left ? Q.i00 : P.i00;
        Rm.r01 = left ? Q.r01 : P.r01; Rm.i01 = left ? Q.i01 : P.i01;
        Rm.r10 = left ? Q.r10 : P.r10; Rm.i10 = left ? Q.i10 : P.i10;
        Rm.r11 = left ? Q.r11 : P.r11; Rm.i11 = left ? Q.i11 : P.i11;
        P = cmm(Lm, Rm);
    }

    if (lane == 0) {
        float r_end = d1v * (1.0f / 2000.0f);
        float Z0e = C1 / (r_end * r_end);
        float kr = k * r_end;
        float ZLr = Z0e * 0.25f * kr * kr;
        float ZLi = Z0e * 0.61f * kr;

        float numr = P.r00*ZLr - P.i00*ZLi + P.r01;
        float numi = P.r00*ZLi + P.i00*ZLr + P.i01;
        float denr = P.r10*ZLr - P.i10*ZLi + P.r11;
        float deni = P.r10*ZLi + P.i10*ZLr + P.i11;

        out[wave] = sqrtf((numr*numr + numi*numi) /
                          (denr*denr + deni*deni));
    }
}

extern "C" void kernel_launch(void* const* d_in, const int* in_sizes, int n_in,
                              void* d_out, int out_size, void* d_ws, size_t ws_size,
                              hipStream_t stream) {
    const float* length = (const float*)d_in[0];
    const float* d1     = (const float*)d_in[1];
    const int*   fmin   = (const int*)d_in[2];
    float* out = (float*)d_out;

    int block = 256;                               // 4 waves = 4 frequencies/block
    int grid = (out_size * 64 + block - 1) / block;
    didge_kernel<<<grid, block, 0, stream>>>(length, d1, fmin, out, out_size);
}

// Round 4
// 9.591 us; speedup vs baseline: 1.2935x; 1.2935x over previous
//
#include <hip/hip_runtime.h>
#include <math.h>

#define N_SUB 128

struct CM { float r00,i00,r01,i01,r10,i10,r11,i11; };

// C = A @ B (complex 2x2), fp32
__device__ inline CM cmm(const CM& A, const CM& B) {
    CM C;
    C.r00 = A.r00*B.r00 - A.i00*B.i00 + A.r01*B.r10 - A.i01*B.i10;
    C.i00 = A.r00*B.i00 + A.i00*B.r00 + A.r01*B.i10 + A.i01*B.r10;
    C.r01 = A.r00*B.r01 - A.i00*B.i01 + A.r01*B.r11 - A.i01*B.i11;
    C.i01 = A.r00*B.i01 + A.i00*B.r01 + A.r01*B.i11 + A.i01*B.r11;
    C.r10 = A.r10*B.r00 - A.i10*B.i00 + A.r11*B.r10 - A.i11*B.i10;
    C.i10 = A.r10*B.i00 + A.i10*B.r00 + A.r11*B.i10 + A.i11*B.r10;
    C.r11 = A.r10*B.r01 - A.i10*B.i01 + A.r11*B.r11 - A.i11*B.i11;
    C.i11 = A.r10*B.i01 + A.i10*B.r01 + A.r11*B.i11 + A.i11*B.r11;
    return C;
}

__device__ inline CM shfl_xor_cm(const CM& P, int mask) {
    CM Q;
    Q.r00 = __shfl_xor(P.r00, mask, 64); Q.i00 = __shfl_xor(P.i00, mask, 64);
    Q.r01 = __shfl_xor(P.r01, mask, 64); Q.i01 = __shfl_xor(P.i01, mask, 64);
    Q.r10 = __shfl_xor(P.r10, mask, 64); Q.i10 = __shfl_xor(P.i10, mask, 64);
    Q.r11 = __shfl_xor(P.r11, mask, 64); Q.i11 = __shfl_xor(P.i11, mask, 64);
    return Q;
}

// v_permlane32_swap_b32: a.lanes[32+i] <-> b.lanes[i].
// With a=b=P on entry: a becomes lo-half broadcast, b becomes hi-half broadcast.
__device__ inline void permswap(float& a, float& b) {
    typedef int v2i __attribute__((ext_vector_type(2)));
    v2i r = __builtin_amdgcn_permlane32_swap(__float_as_int(a), __float_as_int(b),
                                             false, false);
    a = __int_as_float(r.x);
    b = __int_as_float(r.y);
}

__device__ inline CM buildT(int j, float d1v, float sqf, float dL,
                            float cb, float sb) {
    const float PI  = 3.14159265358979323846f;
    const float C1  = 1.2929f * 343.37f / PI;   // RHO*C/pi
    const float IC1 = PI / (1.2929f * 343.37f); // pi/(RHO*C)

    float t = ((float)j + 0.5f) * (1.0f / (float)N_SUB);
    float r = (32.0f + (d1v - 32.0f) * t) * (1.0f / 2000.0f);
    float rinv = __builtin_amdgcn_rcpf(r);
    float a = 3e-5f * sqf * rinv * dL;          // alpha*dL, |a| << 1e-3
    float a2 = a * a;
    float cha = 1.0f + a2 * (0.5f + a2 * (1.0f/24.0f));
    float sha = a * (1.0f + a2 * (1.0f/6.0f + a2 * (1.0f/120.0f)));

    float chr = cha * cb, chi = sha * sb;
    float shr = sha * cb, shi = cha * sb;

    float Z0  = C1 * rinv * rinv;
    float iZ0 = r * r * IC1;

    CM T;
    T.r00 = chr;       T.i00 = chi;
    T.r01 = Z0 * shr;  T.i01 = Z0 * shi;
    T.r10 = iZ0 * shr; T.i10 = iZ0 * shi;
    T.r11 = chr;       T.i11 = chi;
    return T;
}

// One wave (64 lanes) per frequency; lane l owns segments 2l, 2l+1;
// 5 shuffle levels + 1 permlane32_swap level give the ordered 128-product.
__global__ void didge_kernel(const float* __restrict__ length,
                             const float* __restrict__ d1p,
                             const int* __restrict__ fmin_p,
                             float* __restrict__ out, int out_n) {
    int gtid = blockIdx.x * blockDim.x + threadIdx.x;
    int wave = gtid >> 6;
    int lane = gtid & 63;
    if (wave >= out_n) return;  // wave-uniform exit

    const float PI = 3.14159265358979323846f;
    const float C_SOUND = 343.37f;
    const float C1 = 1.2929f * C_SOUND / PI;

    const float f   = (float)fmin_p[0] + (float)wave;
    const float L_m = length[0] * (10.0f / 1000.0f);
    const float d1v = d1p[0];
    const float dL  = L_m * (1.0f / (float)N_SUB);
    const float k   = 2.0f * PI * f * (1.0f / C_SOUND);

    const float b = k * dL;
    float sb, cb;
    __sincosf(b, &sb, &cb);
    const float sqf = __builtin_amdgcn_sqrtf(f);

    // Per-lane pair product: P = T_{2l} @ T_{2l+1}
    CM P = cmm(buildT(2*lane,     d1v, sqf, dL, cb, sb),
               buildT(2*lane + 1, d1v, sqf, dL, cb, sb));

    // Levels 1..16: butterfly with branchless L/R ordering.
    #pragma unroll
    for (int s = 0; s < 5; ++s) {
        int m = 1 << s;
        CM Q = shfl_xor_cm(P, m);
        bool left = (lane & m) == 0;
        CM Lm, Rm;
        Lm.r00 = left ? P.r00 : Q.r00; Lm.i00 = left ? P.i00 : Q.i00;
        Lm.r01 = left ? P.r01 : Q.r01; Lm.i01 = left ? P.i01 : Q.i01;
        Lm.r10 = left ? P.r10 : Q.r10; Lm.i10 = left ? P.i10 : Q.i10;
        Lm.r11 = left ? P.r11 : Q.r11; Lm.i11 = left ? P.i11 : Q.i11;
        Rm.r00 = left ? Q.r00 : P.r00; Rm.i00 = left ? Q.i00 : P.i00;
        Rm.r01 = left ? Q.r01 : P.r01; Rm.i01 = left ? Q.i01 : P.i01;
        Rm.r10 = left ? Q.r10 : P.r10; Rm.i10 = left ? Q.i10 : P.i10;
        Rm.r11 = left ? Q.r11 : P.r11; Rm.i11 = left ? Q.i11 : P.i11;
        P = cmm(Lm, Rm);
    }

    // Level 32: permlane32_swap broadcasts lo-group product (L) and
    // hi-group product (R) to all lanes — no selects, VALU pipe only.
    {
        CM Lh = P, Rh = P;
        permswap(Lh.r00, Rh.r00); permswap(Lh.i00, Rh.i00);
        permswap(Lh.r01, Rh.r01); permswap(Lh.i01, Rh.i01);
        permswap(Lh.r10, Rh.r10); permswap(Lh.i10, Rh.i10);
        permswap(Lh.r11, Rh.r11); permswap(Lh.i11, Rh.i11);
        P = cmm(Lh, Rh);
    }

    if (lane == 0) {
        float r_end = d1v * (1.0f / 2000.0f);
        float Z0e = C1 / (r_end * r_end);
        float kr = k * r_end;
        float ZLr = Z0e * 0.25f * kr * kr;
        float ZLi = Z0e * 0.61f * kr;

        float numr = P.r00*ZLr - P.i00*ZLi + P.r01;
        float numi = P.r00*ZLi + P.i00*ZLr + P.i01;
        float denr = P.r10*ZLr - P.i10*ZLi + P.r11;
        float deni = P.r10*ZLi + P.i10*ZLr + P.i11;

        out[wave] = sqrtf((numr*numr + numi*numi) /
                          (denr*denr + deni*deni));
    }
}

extern "C" void kernel_launch(void* const* d_in, const int* in_sizes, int n_in,
                              void* d_out, int out_size, void* d_ws, size_t ws_size,
                              hipStream_t stream) {
    const float* length = (const float*)d_in[0];
    const float* d1     = (const float*)d_in[1];
    const int*   fmin   = (const int*)d_in[2];
    float* out = (float*)d_out;

    int block = 512;  // 8 waves = 8 frequencies per block
    int grid = (out_size * 64 + block - 1) / block;
    didge_kernel<<<grid, block, 0, stream>>>(length, d1, fmin, out, out_size);
}